// Round 1
// 2483.041 us; speedup vs baseline: 1.0744x; 1.0744x over previous
//
#include <hip/hip_runtime.h>
#include <math.h>
#include <stdint.h>
#include <stddef.h>

// Problem dims (hard-coded per reference)
#define B_ 512
#define H_ 512
#define E_ 512
#define V_ 2048
#define IN_ 1024
#define LSTEPS 32
#define LP1 33

// JAX threefry mode: 1 = partitionable (JAX >= 0.4.36 default), 0 = original
#define TF_PARTITIONABLE 1

// split-K factor for per-step GEMMs
#define SPLITK 4
#define SPLITK_H0 16
#define PSTRIDE_GATES (B_ * 2048)      // 1048576 floats per partial (gates/logits)

__device__ __forceinline__ void tf2x32(uint32_t k0, uint32_t k1,
                                       uint32_t x0, uint32_t x1,
                                       uint32_t& o0, uint32_t& o1) {
  uint32_t ks2 = k0 ^ k1 ^ 0x1BD11BDAu;
  x0 += k0; x1 += k1;
#define TFR(R) { x0 += x1; x1 = (x1 << (R)) | (x1 >> (32 - (R))); x1 ^= x0; }
  TFR(13) TFR(15) TFR(26) TFR(6)
  x0 += k1; x1 += ks2 + 1u;
  TFR(17) TFR(29) TFR(16) TFR(24)
  x0 += ks2; x1 += k0 + 2u;
  TFR(13) TFR(15) TFR(26) TFR(6)
  x0 += k0; x1 += k1 + 3u;
  TFR(17) TFR(29) TFR(16) TFR(24)
  x0 += k1; x1 += ks2 + 4u;
  TFR(13) TFR(15) TFR(26) TFR(6)
  x0 += ks2; x1 += k0 + 5u;
#undef TFR
  o0 = x0; o1 = x1;
}

__global__ void init_keys_kernel(uint32_t* __restrict__ sk) {
  uint32_t k0 = 0u, k1 = 1u;
  for (int t = 0; t < LSTEPS; t++) {
    uint32_t a0, a1, b0, b1;
#if TF_PARTITIONABLE
    tf2x32(k0, k1, 0u, 0u, a0, a1);
    tf2x32(k0, k1, 0u, 1u, b0, b1);
    sk[2 * t] = b0; sk[2 * t + 1] = b1;
    k0 = a0; k1 = a1;
#else
    tf2x32(k0, k1, 0u, 2u, a0, a1);
    tf2x32(k0, k1, 1u, 3u, b0, b1);
    sk[2 * t] = a1; sk[2 * t + 1] = b1;
    k0 = a0; k1 = b0;
#endif
  }
}

__global__ __launch_bounds__(256) void init_state_kernel(
    const float* __restrict__ sos, float* __restrict__ c, float* __restrict__ e) {
  int idx = blockIdx.x * 256 + threadIdx.x;
  if (idx < B_ * H_) {
    c[idx] = 0.0f;
    e[idx] = sos[idx & (E_ - 1)];
  }
}

__global__ __launch_bounds__(256) void eos_fill_kernel(
    float* __restrict__ o_seq, float* __restrict__ o_probs,
    float* __restrict__ o_logp, float* __restrict__ o_ent) {
  int b = blockIdx.x, tid = threadIdx.x;
  float* pr = o_probs + ((size_t)b * LP1 + LSTEPS) * V_;
  for (int v = tid; v < V_; v += 256) pr[v] = 1.0f;
  if (tid == 0) {
    o_seq[b * LP1 + LSTEPS] = 0.0f;
    o_logp[b * LP1 + LSTEPS] = 0.0f;
    o_ent[b * LP1 + LSTEPS] = 0.0f;
  }
}

// ---- async global->LDS staging helper (16B per lane, wave-uniform LDS base)
typedef __attribute__((address_space(1))) const void GASV;
typedef __attribute__((address_space(3))) void LASV;
__device__ __forceinline__ void gld16(const void* g, void* l) {
  __builtin_amdgcn_global_load_lds((GASV*)g, (LASV*)l, 16, 0, 0);
}

// Split-K fp32 GEMM: P[z][128-row tile, 128-col tile] = A[:, kz..kz+KPB) @ B[kz.., :]
// A source: rows m, cols k. k < kHalf -> A0 (stride strideA), else A1 (k-kHalf).
// B source: row k of B0 / B1 (stride N). grid = (M/128, N/128, nsplit).
// 512 threads (8 waves -> 2 waves/SIMD), 8x4 micro-tile, <=128 VGPR,
// double-buffered LDS, all staging via global_load_lds.
__global__ __launch_bounds__(512, 2) void gemm_splitk_kernel(
    const float* __restrict__ A0, const float* __restrict__ A1, int strideA,
    const float* __restrict__ B0, const float* __restrict__ B1,
    int N, int kHalf, int KPB, float* __restrict__ P, int pstride) {
  __shared__ float lds[2][4096];   // per buf: As[128][16] (2048 fl) + Bs[16][128] (2048 fl)
  int tid = threadIdx.x;
  int m0 = blockIdx.x * 128, n0 = blockIdx.y * 128;
  int k0 = blockIdx.z * KPB;
  // blocks never straddle kHalf (KPB divides kHalf in all our uses)
  bool hi = (k0 >= kHalf);
  const float* Ap = hi ? A1 : A0;
  const float* Bp = hi ? B1 : B0;
  int kb = hi ? (k0 - kHalf) : k0;

  int w = tid >> 6, l = tid & 63;
  // A staging: wave w covers As rows [w*16, +16); lane l -> row +l/4, k (l%4)*4
  int arow = w * 16 + (l >> 2);
  int akc = (l & 3) * 4;
  // B staging: wave w covers Bs k-rows [w*2, +2); lane l -> row +l/32, col (l%32)*4
  int bk = w * 2 + (l >> 5);
  int bcol = (l & 31) * 4;

  int ty = tid >> 5;       // 0..15  -> rows ty*4+i and 64+ty*4+i
  int tx = tid & 31;       // 0..31  -> cols tx*4+j

  float acc[8][4] = {};

  int nch = KPB >> 4;      // chunks of BK=16
#define STAGE(CH, TB) {                                                         \
    int kc = kb + ((CH) << 4);                                                  \
    gld16(Ap + (size_t)(m0 + arow) * strideA + kc + akc,                        \
          (char*)&lds[TB][0] + w * 1024);                                       \
    gld16(Bp + (size_t)(kc + bk) * N + n0 + bcol,                               \
          (char*)&lds[TB][2048] + w * 1024);                                    \
  }

  STAGE(0, 0)
  for (int ch = 0; ch < nch; ch++) {
    __syncthreads();                 // drains vmcnt -> buf[ch&1] ready
    if (ch + 1 < nch) STAGE(ch + 1, (ch + 1) & 1)
    const float* As = &lds[ch & 1][0];
    const float* Bs = &lds[ch & 1][2048];
#pragma unroll
    for (int kg = 0; kg < 4; kg++) {
      float4 a[8], b[4];
#pragma unroll
      for (int i = 0; i < 4; i++) {
        a[i]     = *(const float4*)&As[(ty * 4 + i) * 16 + kg * 4];
        a[i + 4] = *(const float4*)&As[(ty * 4 + i + 64) * 16 + kg * 4];
      }
#pragma unroll
      for (int kk = 0; kk < 4; kk++)
        b[kk] = *(const float4*)&Bs[(kg * 4 + kk) * 128 + tx * 4];
#pragma unroll
      for (int kk = 0; kk < 4; kk++) {
#pragma unroll
        for (int i = 0; i < 8; i++) {
          float av = ((const float*)&a[i])[kk];
#pragma unroll
          for (int j = 0; j < 4; j++)
            acc[i][j] += av * ((const float*)&b[kk])[j];
        }
      }
    }
  }
#undef STAGE

  float* Pb = P + (size_t)blockIdx.z * pstride;
#pragma unroll
  for (int i = 0; i < 8; i++) {
    int row = m0 + ((i < 4) ? (ty * 4 + i) : (64 + ty * 4 + i - 4));
    float4 o;
    o.x = acc[i][0]; o.y = acc[i][1]; o.z = acc[i][2]; o.w = acc[i][3];
    *(float4*)&Pb[(size_t)row * N + n0 + tx * 4] = o;
  }
}

__device__ __forceinline__ float sigm(float x) { return 1.0f / (1.0f + expf(-x)); }

// Sum SPLITK gate partials + biases, apply LSTM cell. One float4 of H per thread.
__global__ __launch_bounds__(256) void cell_reduce_kernel(
    const float* __restrict__ P,
    const float* __restrict__ b_ih, const float* __restrict__ b_hh,
    float* __restrict__ c, float* __restrict__ h) {
  int idx = blockIdx.x * 256 + threadIdx.x;   // float4 index in [B, H] space
  int b = idx >> 7;
  int h4 = (idx & 127) * 4;
  float4 g4[4];
#pragma unroll
  for (int g = 0; g < 4; g++) {
    size_t off = (size_t)b * 2048 + g * 512 + h4;
    float4 s = *(const float4*)&P[off];
#pragma unroll
    for (int sgl = 1; sgl < SPLITK; sgl++) {
      float4 p = *(const float4*)&P[(size_t)sgl * PSTRIDE_GATES + off];
      s.x += p.x; s.y += p.y; s.z += p.z; s.w += p.w;
    }
    float4 bi = *(const float4*)&b_ih[g * 512 + h4];
    float4 bh = *(const float4*)&b_hh[g * 512 + h4];
    s.x += bi.x + bh.x; s.y += bi.y + bh.y; s.z += bi.z + bh.z; s.w += bi.w + bh.w;
    g4[g] = s;
  }
  size_t ci = (size_t)b * 512 + h4;
  float4 cold = *(const float4*)&c[ci];
  float4 cn, hn;
  {
    const float* ig = (const float*)&g4[0];
    const float* fg = (const float*)&g4[1];
    const float* gg = (const float*)&g4[2];
    const float* og = (const float*)&g4[3];
    float* cc = (float*)&cn; float* hh = (float*)&hn;
    const float* co = (const float*)&cold;
#pragma unroll
    for (int k = 0; k < 4; k++) {
      float cv = sigm(fg[k]) * co[k] + sigm(ig[k]) * tanhf(gg[k]);
      cc[k] = cv;
      hh[k] = sigm(og[k]) * tanhf(cv);
    }
  }
  *(float4*)&c[ci] = cn;
  *(float4*)&h[ci] = hn;
}

// Sum nsplit partials + bias -> out (used once for h0). N = row width.
__global__ __launch_bounds__(256) void reduce_bias_kernel(
    const float* __restrict__ P, int pstride, int nsplit,
    const float* __restrict__ bias,
    float* __restrict__ out, int N, int total4) {
  int idx = blockIdx.x * 256 + threadIdx.x;
  if (idx >= total4) return;
  size_t off = (size_t)idx * 4;
  float4 s = *(const float4*)&P[off];
  for (int sgl = 1; sgl < nsplit; sgl++) {
    float4 p = *(const float4*)&P[(size_t)sgl * pstride + off];
    s.x += p.x; s.y += p.y; s.z += p.z; s.w += p.w;
  }
  int col = (int)(off % N);
  float4 bv = *(const float4*)&bias[col];
  s.x += bv.x; s.y += bv.y; s.z += bv.z; s.w += bv.w;
  *(float4*)&out[off] = s;
}

// Per-row: reduce logits partials (+out_b), log_softmax, entropy, probs write,
// threefry gumbel argmax sample, logp gather, embedding gather. One block/row.
__global__ __launch_bounds__(256) void sample_step_kernel(
    const float* __restrict__ P, const float* __restrict__ out_b,
    const uint32_t* __restrict__ skv,
    const float* __restrict__ embedding, float* __restrict__ e,
    float* __restrict__ o_seq, float* __restrict__ o_probs,
    float* __restrict__ o_logp, float* __restrict__ o_ent, int t) {
  __shared__ float zs[V_];
  __shared__ float rmax[4], rsum[4], rps[4], rav[4];
  __shared__ int rai[4];
  int tid = threadIdx.x, b = blockIdx.x;
  int wid = tid >> 6;
  const float* pr0 = P + (size_t)b * V_ + tid * 8;
  float4 za = *(const float4*)pr0;
  float4 zb = *(const float4*)(pr0 + 4);
#pragma unroll
  for (int s = 1; s < SPLITK; s++) {
    float4 pa = *(const float4*)(pr0 + (size_t)s * PSTRIDE_GATES);
    float4 pb = *(const float4*)(pr0 + (size_t)s * PSTRIDE_GATES + 4);
    za.x += pa.x; za.y += pa.y; za.z += pa.z; za.w += pa.w;
    zb.x += pb.x; zb.y += pb.y; zb.z += pb.z; zb.w += pb.w;
  }
  {
    float4 oa = *(const float4*)(out_b + tid * 8);
    float4 ob = *(const float4*)(out_b + tid * 8 + 4);
    za.x += oa.x; za.y += oa.y; za.z += oa.z; za.w += oa.w;
    zb.x += ob.x; zb.y += ob.y; zb.z += ob.z; zb.w += ob.w;
  }
  float zv[8] = {za.x, za.y, za.z, za.w, zb.x, zb.y, zb.z, zb.w};
  *(float4*)&zs[tid * 8] = za;
  *(float4*)&zs[tid * 8 + 4] = zb;

  float m = zv[0];
#pragma unroll
  for (int i = 1; i < 8; i++) m = fmaxf(m, zv[i]);
  for (int off = 32; off; off >>= 1) m = fmaxf(m, __shfl_xor(m, off));
  if ((tid & 63) == 0) rmax[wid] = m;
  __syncthreads();
  m = fmaxf(fmaxf(rmax[0], rmax[1]), fmaxf(rmax[2], rmax[3]));

  float sh[8];
  float ssum = 0.f;
#pragma unroll
  for (int i = 0; i < 8; i++) { sh[i] = zv[i] - m; ssum += expf(sh[i]); }
  for (int off = 32; off; off >>= 1) ssum += __shfl_xor(ssum, off);
  if ((tid & 63) == 0) rsum[wid] = ssum;
  __syncthreads();
  float S = (rsum[0] + rsum[1]) + (rsum[2] + rsum[3]);
  float ls = logf(S);

  uint32_t sk0 = skv[2 * t], sk1 = skv[2 * t + 1];
  float psum = 0.f;
  float best = -INFINITY;
  int bi = 0;
  float pv[8];
#pragma unroll
  for (int i = 0; i < 8; i++) {
    float s = sh[i] - ls;
    float p = expf(s);
    pv[i] = p;
    psum += p * s;
    int v = tid * 8 + i;
    uint32_t o0, o1, bits;
#if TF_PARTITIONABLE
    uint32_t j = (uint32_t)(b * V_ + v);
    tf2x32(sk0, sk1, 0u, j, o0, o1);
    bits = o0 ^ o1;
#else
    uint32_t j = (uint32_t)(b * V_ + v);
    const uint32_t n2 = (uint32_t)(B_ * V_ / 2);
    if (j < n2) { tf2x32(sk0, sk1, j, j + n2, o0, o1); bits = o0; }
    else       { tf2x32(sk0, sk1, j - n2, j, o0, o1); bits = o1; }
#endif
    float f = __uint_as_float((bits >> 9) | 0x3f800000u) - 1.0f;
    float u = fmaxf(f, 1.17549435e-38f);
    float g = -logf(-logf(u));
    float a = s + g;
    if (a > best) { best = a; bi = v; }
  }
  float* prw = o_probs + ((size_t)b * LP1 + t) * V_ + tid * 8;
  *(float4*)prw = make_float4(pv[0], pv[1], pv[2], pv[3]);
  *(float4*)(prw + 4) = make_float4(pv[4], pv[5], pv[6], pv[7]);

  for (int off = 32; off; off >>= 1) psum += __shfl_xor(psum, off);
  for (int off = 32; off; off >>= 1) {
    float ov = __shfl_xor(best, off);
    int oi = __shfl_xor(bi, off);
    if (ov > best || (ov == best && oi < bi)) { best = ov; bi = oi; }
  }
  if ((tid & 63) == 0) { rps[wid] = psum; rav[wid] = best; rai[wid] = bi; }
  __syncthreads();
  float ent = -((rps[0] + rps[1]) + (rps[2] + rps[3]));
  float bv2 = rav[0]; int sym = rai[0];
#pragma unroll
  for (int w2 = 1; w2 < 4; w2++) {
    if (rav[w2] > bv2 || (rav[w2] == bv2 && rai[w2] < sym)) { bv2 = rav[w2]; sym = rai[w2]; }
  }
  const float* em = embedding + (size_t)sym * E_;
  for (int k2 = tid; k2 < E_; k2 += 256) e[(size_t)b * E_ + k2] = em[k2];
  if (tid == 0) {
    float s_sym = (zs[sym] - m) - ls;
    o_seq[b * LP1 + t] = (float)sym;
    o_logp[b * LP1 + t] = s_sym;
    o_ent[b * LP1 + t] = ent;
  }
}

extern "C" void kernel_launch(void* const* d_in, const int* in_sizes, int n_in,
                              void* d_out, int out_size, void* d_ws, size_t ws_size,
                              hipStream_t stream) {
  (void)in_sizes; (void)n_in; (void)out_size; (void)ws_size;
  const float* x     = (const float*)d_in[0];
  const float* agw   = (const float*)d_in[1];
  const float* agb   = (const float*)d_in[2];
  const float* sos   = (const float*)d_in[3];
  const float* emb   = (const float*)d_in[4];
  const float* w_ih  = (const float*)d_in[5];
  const float* w_hh  = (const float*)d_in[6];
  const float* b_ih  = (const float*)d_in[7];
  const float* b_hh  = (const float*)d_in[8];
  const float* out_w = (const float*)d_in[9];
  const float* out_b = (const float*)d_in[10];

  char* w = (char*)d_ws;
  uint32_t* sk = (uint32_t*)w;                                // 256 B used
  float* e  = (float*)(w + 1024);                             // 1 MB
  float* hA = (float*)(w + 1024 + 1 * 1048576);               // 1 MB
  float* hB = (float*)(w + 1024 + 2 * 1048576);               // 1 MB
  float* c  = (float*)(w + 1024 + 3 * 1048576);               // 1 MB
  float* P  = (float*)(w + 1024 + 4 * 1048576);               // 16 MB partials

  float* out = (float*)d_out;
  float* o_seq   = out;                                       // [512,33]
  float* o_probs = out + (size_t)B_ * LP1;                    // [512,33,2048]
  float* o_logp  = o_probs + (size_t)B_ * LP1 * V_;           // [512,33]
  float* o_ent   = o_logp + (size_t)B_ * LP1;                 // [512,33]

  const int BIG = 1 << 30;

  init_keys_kernel<<<1, 1, 0, stream>>>(sk);
  init_state_kernel<<<(B_ * H_ + 255) / 256, 256, 0, stream>>>(sos, c, e);
  eos_fill_kernel<<<B_, 256, 0, stream>>>(o_seq, o_probs, o_logp, o_ent);

  // h0 = x @ agent_w + agent_b   (M=512,N=512,K=1024; split-K 16, KPB=64 -> 256 blocks)
  gemm_splitk_kernel<<<dim3(B_ / 128, H_ / 128, SPLITK_H0), 512, 0, stream>>>(
      x, x, IN_, agw, agw, H_, BIG, IN_ / SPLITK_H0, P, B_ * H_);
  reduce_bias_kernel<<<(B_ * H_ / 4 + 255) / 256, 256, 0, stream>>>(
      P, B_ * H_, SPLITK_H0, agb, hA, H_, B_ * H_ / 4);

  for (int t = 0; t < LSTEPS; t++) {
    float* hin  = (t & 1) ? hB : hA;
    float* hout = (t & 1) ? hA : hB;
    // gates = [e|h] @ [w_ih; w_hh]  (K=1024, KPB=256, kHalf=512)
    gemm_splitk_kernel<<<dim3(B_ / 128, 2048 / 128, SPLITK), 512, 0, stream>>>(
        e, hin, E_, w_ih, w_hh, 4 * H_, E_, (E_ + H_) / SPLITK, P, PSTRIDE_GATES);
    cell_reduce_kernel<<<B_ * H_ / 4 / 256, 256, 0, stream>>>(P, b_ih, b_hh, c, hout);
    // logits partials = h @ out_w  (K=512, KPB=128)
    gemm_splitk_kernel<<<dim3(B_ / 128, V_ / 128, SPLITK), 512, 0, stream>>>(
        hout, hout, H_, out_w, out_w, V_, BIG, H_ / SPLITK, P, PSTRIDE_GATES);
    sample_step_kernel<<<B_, 256, 0, stream>>>(
        P, out_b, sk, emb, e, o_seq, o_probs, o_logp, o_ent, t);
  }
}

// Round 2
// 1722.910 us; speedup vs baseline: 1.5484x; 1.4412x over previous
//
#include <hip/hip_runtime.h>
#include <math.h>
#include <stdint.h>
#include <stddef.h>

// Problem dims (hard-coded per reference)
#define B_ 512
#define H_ 512
#define E_ 512
#define V_ 2048
#define IN_ 1024
#define LSTEPS 32
#define LP1 33

// JAX threefry mode: 1 = partitionable (JAX >= 0.4.36 default), 0 = original
#define TF_PARTITIONABLE 1

#define SPLITK 4
#define SPLITK_H0 16
#define PSTRIDE_GATES (B_ * 2048)      // floats per partial (gates/logits)
#define PSTRIDE_H0 (B_ * H_)

typedef unsigned short u16;
typedef __attribute__((ext_vector_type(8))) short bhalf8;   // 8 bf16 = 4 VGPR
typedef __attribute__((ext_vector_type(4))) float f32x4;

__device__ __forceinline__ void tf2x32(uint32_t k0, uint32_t k1,
                                       uint32_t x0, uint32_t x1,
                                       uint32_t& o0, uint32_t& o1) {
  uint32_t ks2 = k0 ^ k1 ^ 0x1BD11BDAu;
  x0 += k0; x1 += k1;
#define TFR(R) { x0 += x1; x1 = (x1 << (R)) | (x1 >> (32 - (R))); x1 ^= x0; }
  TFR(13) TFR(15) TFR(26) TFR(6)
  x0 += k1; x1 += ks2 + 1u;
  TFR(17) TFR(29) TFR(16) TFR(24)
  x0 += ks2; x1 += k0 + 2u;
  TFR(13) TFR(15) TFR(26) TFR(6)
  x0 += k0; x1 += k1 + 3u;
  TFR(17) TFR(29) TFR(16) TFR(24)
  x0 += k1; x1 += ks2 + 4u;
  TFR(13) TFR(15) TFR(26) TFR(6)
  x0 += ks2; x1 += k0 + 5u;
#undef TFR
  o0 = x0; o1 = x1;
}

__global__ void init_keys_kernel(uint32_t* __restrict__ sk) {
  uint32_t k0 = 0u, k1 = 1u;
  for (int t = 0; t < LSTEPS; t++) {
    uint32_t a0, a1, b0, b1;
#if TF_PARTITIONABLE
    tf2x32(k0, k1, 0u, 0u, a0, a1);
    tf2x32(k0, k1, 0u, 1u, b0, b1);
    sk[2 * t] = b0; sk[2 * t + 1] = b1;
    k0 = a0; k1 = a1;
#else
    tf2x32(k0, k1, 0u, 2u, a0, a1);
    tf2x32(k0, k1, 1u, 3u, b0, b1);
    sk[2 * t] = a1; sk[2 * t + 1] = b1;
    k0 = a0; k1 = b0;
#endif
  }
}

// ---- bf16x3 split (RNE at each stage; hi+mid+lo represents fp32 to 2^-27)
__device__ __forceinline__ void split3(float v, u16& h, u16& m, u16& l) {
  uint32_t u = __float_as_uint(v);
  uint32_t r = (u + 0x7FFFu + ((u >> 16) & 1u)) >> 16;
  h = (u16)r;
  float res = v - __uint_as_float(r << 16);
  uint32_t u2 = __float_as_uint(res);
  uint32_t r2 = (u2 + 0x7FFFu + ((u2 >> 16) & 1u)) >> 16;
  m = (u16)r2;
  float res2 = res - __uint_as_float(r2 << 16);
  uint32_t u3 = __float_as_uint(res2);
  uint32_t r3 = (u3 + 0x7FFFu + ((u3 >> 16) & 1u)) >> 16;
  l = (u16)r3;
}

__global__ __launch_bounds__(256) void init_state_planes_kernel(
    const float* __restrict__ sos, float* __restrict__ c,
    u16* __restrict__ eh, u16* __restrict__ em, u16* __restrict__ el) {
  int idx = blockIdx.x * 256 + threadIdx.x;
  if (idx < B_ * H_) {
    c[idx] = 0.0f;
    u16 a, b2, d;
    split3(sos[idx & (E_ - 1)], a, b2, d);
    eh[idx] = a; em[idx] = b2; el[idx] = d;
  }
}

__global__ __launch_bounds__(256) void eos_fill_kernel(
    float* __restrict__ o_seq, float* __restrict__ o_probs,
    float* __restrict__ o_logp, float* __restrict__ o_ent) {
  int b = blockIdx.x, tid = threadIdx.x;
  float* pr = o_probs + ((size_t)b * LP1 + LSTEPS) * V_;
  for (int v = tid; v < V_; v += 256) pr[v] = 1.0f;
  if (tid == 0) {
    o_seq[b * LP1 + LSTEPS] = 0.0f;
    o_logp[b * LP1 + LSTEPS] = 0.0f;
    o_ent[b * LP1 + LSTEPS] = 0.0f;
  }
}

// elementwise fp32 -> 3 bf16 planes (same layout)
__global__ __launch_bounds__(256) void split_kernel(
    const float* __restrict__ src,
    u16* __restrict__ dh, u16* __restrict__ dm, u16* __restrict__ dl, int n) {
  int i = blockIdx.x * 256 + threadIdx.x;
  if (i < n) {
    u16 a, b2, d;
    split3(src[i], a, b2, d);
    dh[i] = a; dm[i] = b2; dl[i] = d;
  }
}

// src [srcK][srcN] fp32 -> dst planes [srcN][dstK] bf16 at column offset kOff
__global__ __launch_bounds__(256) void transpose_split_kernel(
    const float* __restrict__ src, int srcN,
    u16* __restrict__ dh, u16* __restrict__ dm, u16* __restrict__ dl,
    int dstK, int kOff) {
  __shared__ float t[32][33];
  int tx = threadIdx.x & 31, ty = threadIdx.x >> 5;   // 32 x 8
  int kt = blockIdx.x * 32, nt = blockIdx.y * 32;
#pragma unroll
  for (int j = 0; j < 4; j++)
    t[ty + j * 8][tx] = src[(size_t)(kt + ty + j * 8) * srcN + nt + tx];
  __syncthreads();
#pragma unroll
  for (int j = 0; j < 4; j++) {
    int n = nt + ty + j * 8;
    int k = kt + tx;
    u16 a, b2, d;
    split3(t[tx][ty + j * 8], a, b2, d);
    size_t o = (size_t)n * dstK + kOff + k;
    dh[o] = a; dm[o] = b2; dl[o] = d;
  }
}

// ---- async global->LDS staging helper (16B per lane, wave-uniform LDS base)
typedef __attribute__((address_space(1))) const void GASV;
typedef __attribute__((address_space(3))) void LASV;
__device__ __forceinline__ void gld16(const void* g, void* l) {
  __builtin_amdgcn_global_load_lds((GASV*)g, (LASV*)l, 16, 0, 0);
}

// bf16x3 split-K MFMA GEMM. C = A @ B^T-stored-B.
// A planes: [M][Kpart] bf16 (k-contig). k < kHalf -> A0*, else A1* (k-kHalf).
// B planes: [N][Ktot] bf16 (k-contig, pre-transposed).
// grid = (M/128, N/128, nsplit), 256 threads, wave-tile 64x64, acc 4x4 frags.
// LDS: 2 bufs x 6 planes x [128 rows][32 k] bf16, slot-swizzled:
//   stored_byte(r, s) = r*64 + ((s ^ ((r>>1)&3)) << 4)   (s = k>>3 slot)
__global__ __launch_bounds__(256, 1) void gemm3_kernel(
    const u16* __restrict__ A0h, const u16* __restrict__ A0m, const u16* __restrict__ A0l,
    const u16* __restrict__ A1h, const u16* __restrict__ A1m, const u16* __restrict__ A1l,
    int strideA, int kHalf,
    const u16* __restrict__ Bh, const u16* __restrict__ Bm, const u16* __restrict__ Bl,
    int strideB, int N, int KPB,
    float* __restrict__ P, int pstride) {
  __shared__ u16 lds[2][6][4096];   // 96 KB
  int tid = threadIdx.x;
  int w = tid >> 6, l = tid & 63;
  int m0 = blockIdx.x * 128, n0 = blockIdx.y * 128;
  int k0 = blockIdx.z * KPB;
  bool hi = (k0 >= kHalf);
  const u16* Ah = hi ? A1h : A0h;
  const u16* Am = hi ? A1m : A0m;
  const u16* Al = hi ? A1l : A0l;
  int kb = hi ? (k0 - kHalf) : k0;

  // staging decode: wave w stages row-segments {w*2, w*2+1} of every plane.
  // lane i -> stored row seg*16 + (i>>2), stored slot i&3; the logical k-group
  // that must land there is (i&3) ^ ((i>>3)&3)  (inverse of the read swizzle).
  int srow = l >> 2;
  int slog = (l & 3) ^ ((l >> 3) & 3);
  int seg0 = w * 2, seg1 = w * 2 + 1;
  size_t aG0 = (size_t)(m0 + seg0 * 16 + srow) * strideA + slog * 8;
  size_t aG1 = (size_t)(m0 + seg1 * 16 + srow) * strideA + slog * 8;
  size_t bG0 = (size_t)(n0 + seg0 * 16 + srow) * strideB + slog * 8;
  size_t bG1 = (size_t)(n0 + seg1 * 16 + srow) * strideB + slog * 8;

  // compute decode: wave (wr,wc) owns 64x64; frag reads swizzled.
  int wr = (w >> 1) * 64, wc = (w & 1) * 64;
  int lrow = l & 15, lk8 = l >> 4;
  int xorv = (lrow >> 1) & 3;
  int fOffA = (wr + lrow) * 64 + ((lk8 ^ xorv) << 4);
  int fOffB = (wc + lrow) * 64 + ((lk8 ^ xorv) << 4);

  f32x4 acc[4][4] = {};
  int nch = KPB >> 5;

#define STAGE3(CH, TB) {                                                  \
    int kca = kb + ((CH) << 5);                                           \
    int kcb = k0 + ((CH) << 5);                                           \
    char* Lb = (char*)&lds[TB][0][0];                                     \
    gld16(Ah + aG0 + kca, Lb + 0 * 8192 + seg0 * 1024);                   \
    gld16(Ah + aG1 + kca, Lb + 0 * 8192 + seg1 * 1024);                   \
    gld16(Am + aG0 + kca, Lb + 1 * 8192 + seg0 * 1024);                   \
    gld16(Am + aG1 + kca, Lb + 1 * 8192 + seg1 * 1024);                   \
    gld16(Al + aG0 + kca, Lb + 2 * 8192 + seg0 * 1024);                   \
    gld16(Al + aG1 + kca, Lb + 2 * 8192 + seg1 * 1024);                   \
    gld16(Bh + bG0 + kcb, Lb + 3 * 8192 + seg0 * 1024);                   \
    gld16(Bh + bG1 + kcb, Lb + 3 * 8192 + seg1 * 1024);                   \
    gld16(Bm + bG0 + kcb, Lb + 4 * 8192 + seg0 * 1024);                   \
    gld16(Bm + bG1 + kcb, Lb + 4 * 8192 + seg1 * 1024);                   \
    gld16(Bl + bG0 + kcb, Lb + 5 * 8192 + seg0 * 1024);                   \
    gld16(Bl + bG1 + kcb, Lb + 5 * 8192 + seg1 * 1024);                   \
  }

  STAGE3(0, 0)
  for (int ch = 0; ch < nch; ch++) {
    __syncthreads();                 // drains vmcnt -> buf[ch&1] staged
    if (ch + 1 < nch) STAGE3(ch + 1, (ch + 1) & 1)
    const char* base = (const char*)&lds[ch & 1][0][0];
    bhalf8 af[3][4], bfr[3][4];
#pragma unroll
    for (int p = 0; p < 3; p++) {
#pragma unroll
      for (int m = 0; m < 4; m++)
        af[p][m] = *(const bhalf8*)(base + p * 8192 + fOffA + m * 1024);
#pragma unroll
      for (int n = 0; n < 4; n++)
        bfr[p][n] = *(const bhalf8*)(base + (3 + p) * 8192 + fOffB + n * 1024);
    }
    // 6-term bf16x3: accumulate small terms first.
    const int PA[6] = {2, 0, 1, 1, 0, 0};
    const int PB[6] = {0, 2, 1, 0, 1, 0};
#pragma unroll
    for (int pp = 0; pp < 6; pp++) {
#pragma unroll
      for (int m = 0; m < 4; m++) {
#pragma unroll
        for (int n = 0; n < 4; n++) {
          acc[m][n] = __builtin_amdgcn_mfma_f32_16x16x32_bf16(
              af[PA[pp]][m], bfr[PB[pp]][n], acc[m][n], 0, 0, 0);
        }
      }
    }
  }
#undef STAGE3

  // C/D layout: col = lane&15, row = (lane>>4)*4 + reg  [m89-verified]
  float* Pb = P + (size_t)blockIdx.z * pstride;
#pragma unroll
  for (int m = 0; m < 4; m++) {
#pragma unroll
    for (int n = 0; n < 4; n++) {
#pragma unroll
      for (int j = 0; j < 4; j++) {
        int row = m0 + wr + m * 16 + lk8 * 4 + j;
        int col = n0 + wc + n * 16 + lrow;
        Pb[(size_t)row * N + col] = acc[m][n][j];
      }
    }
  }
}

__device__ __forceinline__ float sigm(float x) { return 1.0f / (1.0f + expf(-x)); }

// Sum SPLITK gate partials + biases, apply LSTM cell; write c fp32 and h planes.
__global__ __launch_bounds__(256) void cell_reduce_planes_kernel(
    const float* __restrict__ P,
    const float* __restrict__ b_ih, const float* __restrict__ b_hh,
    float* __restrict__ c,
    u16* __restrict__ hh_, u16* __restrict__ hm_, u16* __restrict__ hl_) {
  int idx = blockIdx.x * 256 + threadIdx.x;   // float4 index in [B, H] space
  int b = idx >> 7;
  int h4 = (idx & 127) * 4;
  float4 g4[4];
#pragma unroll
  for (int g = 0; g < 4; g++) {
    size_t off = (size_t)b * 2048 + g * 512 + h4;
    float4 s = *(const float4*)&P[off];
#pragma unroll
    for (int sgl = 1; sgl < SPLITK; sgl++) {
      float4 p = *(const float4*)&P[(size_t)sgl * PSTRIDE_GATES + off];
      s.x += p.x; s.y += p.y; s.z += p.z; s.w += p.w;
    }
    float4 bi = *(const float4*)&b_ih[g * 512 + h4];
    float4 bh = *(const float4*)&b_hh[g * 512 + h4];
    s.x += bi.x + bh.x; s.y += bi.y + bh.y; s.z += bi.z + bh.z; s.w += bi.w + bh.w;
    g4[g] = s;
  }
  size_t ci = (size_t)b * 512 + h4;
  float4 cold = *(const float4*)&c[ci];
  float4 cn;
  float hv[4];
  {
    const float* ig = (const float*)&g4[0];
    const float* fg = (const float*)&g4[1];
    const float* gg = (const float*)&g4[2];
    const float* og = (const float*)&g4[3];
    float* cc = (float*)&cn;
    const float* co = (const float*)&cold;
#pragma unroll
    for (int k = 0; k < 4; k++) {
      float cv = sigm(fg[k]) * co[k] + sigm(ig[k]) * tanhf(gg[k]);
      cc[k] = cv;
      hv[k] = sigm(og[k]) * tanhf(cv);
    }
  }
  *(float4*)&c[ci] = cn;
  ushort4 vh, vm, vl;
  u16 a, b2, d;
  split3(hv[0], a, b2, d); vh.x = a; vm.x = b2; vl.x = d;
  split3(hv[1], a, b2, d); vh.y = a; vm.y = b2; vl.y = d;
  split3(hv[2], a, b2, d); vh.z = a; vm.z = b2; vl.z = d;
  split3(hv[3], a, b2, d); vh.w = a; vm.w = b2; vl.w = d;
  *(ushort4*)&hh_[ci] = vh;
  *(ushort4*)&hm_[ci] = vm;
  *(ushort4*)&hl_[ci] = vl;
}

// Sum nsplit partials + bias -> h planes (used once for h0).
__global__ __launch_bounds__(256) void reduce_bias_planes_kernel(
    const float* __restrict__ P, int pstride, int nsplit,
    const float* __restrict__ bias,
    u16* __restrict__ oh, u16* __restrict__ om, u16* __restrict__ ol) {
  int idx = blockIdx.x * 256 + threadIdx.x;
  if (idx >= B_ * H_ / 4) return;
  size_t off = (size_t)idx * 4;
  float4 s = *(const float4*)&P[off];
  for (int sgl = 1; sgl < nsplit; sgl++) {
    float4 p = *(const float4*)&P[(size_t)sgl * pstride + off];
    s.x += p.x; s.y += p.y; s.z += p.z; s.w += p.w;
  }
  int col = (int)(off & (H_ - 1));
  float4 bv = *(const float4*)&bias[col];
  s.x += bv.x; s.y += bv.y; s.z += bv.z; s.w += bv.w;
  ushort4 vh, vm, vl;
  u16 a, b2, d;
  split3(s.x, a, b2, d); vh.x = a; vm.x = b2; vl.x = d;
  split3(s.y, a, b2, d); vh.y = a; vm.y = b2; vl.y = d;
  split3(s.z, a, b2, d); vh.z = a; vm.z = b2; vl.z = d;
  split3(s.w, a, b2, d); vh.w = a; vm.w = b2; vl.w = d;
  *(ushort4*)&oh[off] = vh;
  *(ushort4*)&om[off] = vm;
  *(ushort4*)&ol[off] = vl;
}

// Per-row: reduce logits partials (+out_b), log_softmax, entropy, probs write,
// threefry gumbel argmax sample, logp gather, embedding-plane gather.
__global__ __launch_bounds__(256) void sample_step_kernel(
    const float* __restrict__ P, const float* __restrict__ out_b,
    const uint32_t* __restrict__ skv,
    const u16* __restrict__ ebH, const u16* __restrict__ ebM, const u16* __restrict__ ebL,
    u16* __restrict__ eh, u16* __restrict__ em_, u16* __restrict__ el_,
    float* __restrict__ o_seq, float* __restrict__ o_probs,
    float* __restrict__ o_logp, float* __restrict__ o_ent, int t) {
  __shared__ float zs[V_];
  __shared__ float rmax[4], rsum[4], rps[4], rav[4];
  __shared__ int rai[4];
  int tid = threadIdx.x, b = blockIdx.x;
  int wid = tid >> 6;
  const float* pr0 = P + (size_t)b * V_ + tid * 8;
  float4 za = *(const float4*)pr0;
  float4 zb = *(const float4*)(pr0 + 4);
#pragma unroll
  for (int s = 1; s < SPLITK; s++) {
    float4 pa = *(const float4*)(pr0 + (size_t)s * PSTRIDE_GATES);
    float4 pb = *(const float4*)(pr0 + (size_t)s * PSTRIDE_GATES + 4);
    za.x += pa.x; za.y += pa.y; za.z += pa.z; za.w += pa.w;
    zb.x += pb.x; zb.y += pb.y; zb.z += pb.z; zb.w += pb.w;
  }
  {
    float4 oa = *(const float4*)(out_b + tid * 8);
    float4 ob = *(const float4*)(out_b + tid * 8 + 4);
    za.x += oa.x; za.y += oa.y; za.z += oa.z; za.w += oa.w;
    zb.x += ob.x; zb.y += ob.y; zb.z += ob.z; zb.w += ob.w;
  }
  float zv[8] = {za.x, za.y, za.z, za.w, zb.x, zb.y, zb.z, zb.w};
  *(float4*)&zs[tid * 8] = za;
  *(float4*)&zs[tid * 8 + 4] = zb;

  float m = zv[0];
#pragma unroll
  for (int i = 1; i < 8; i++) m = fmaxf(m, zv[i]);
  for (int off = 32; off; off >>= 1) m = fmaxf(m, __shfl_xor(m, off));
  if ((tid & 63) == 0) rmax[wid] = m;
  __syncthreads();
  m = fmaxf(fmaxf(rmax[0], rmax[1]), fmaxf(rmax[2], rmax[3]));

  float sh[8];
  float ssum = 0.f;
#pragma unroll
  for (int i = 0; i < 8; i++) { sh[i] = zv[i] - m; ssum += expf(sh[i]); }
  for (int off = 32; off; off >>= 1) ssum += __shfl_xor(ssum, off);
  if ((tid & 63) == 0) rsum[wid] = ssum;
  __syncthreads();
  float S = (rsum[0] + rsum[1]) + (rsum[2] + rsum[3]);
  float ls = logf(S);

  uint32_t sk0 = skv[2 * t], sk1 = skv[2 * t + 1];
  float psum = 0.f;
  float best = -INFINITY;
  int bi = 0;
  float pv[8];
#pragma unroll
  for (int i = 0; i < 8; i++) {
    float s = sh[i] - ls;
    float p = expf(s);
    pv[i] = p;
    psum += p * s;
    int v = tid * 8 + i;
    uint32_t o0, o1, bits;
#if TF_PARTITIONABLE
    uint32_t j = (uint32_t)(b * V_ + v);
    tf2x32(sk0, sk1, 0u, j, o0, o1);
    bits = o0 ^ o1;
#else
    uint32_t j = (uint32_t)(b * V_ + v);
    const uint32_t n2 = (uint32_t)(B_ * V_ / 2);
    if (j < n2) { tf2x32(sk0, sk1, j, j + n2, o0, o1); bits = o0; }
    else       { tf2x32(sk0, sk1, j - n2, j, o0, o1); bits = o1; }
#endif
    float f = __uint_as_float((bits >> 9) | 0x3f800000u) - 1.0f;
    float u = fmaxf(f, 1.17549435e-38f);
    float g = -logf(-logf(u));
    float a = s + g;
    if (a > best) { best = a; bi = v; }
  }
  float* prw = o_probs + ((size_t)b * LP1 + t) * V_ + tid * 8;
  *(float4*)prw = make_float4(pv[0], pv[1], pv[2], pv[3]);
  *(float4*)(prw + 4) = make_float4(pv[4], pv[5], pv[6], pv[7]);

  for (int off = 32; off; off >>= 1) psum += __shfl_xor(psum, off);
  for (int off = 32; off; off >>= 1) {
    float ov = __shfl_xor(best, off);
    int oi = __shfl_xor(bi, off);
    if (ov > best || (ov == best && oi < bi)) { best = ov; bi = oi; }
  }
  if ((tid & 63) == 0) { rps[wid] = psum; rav[wid] = best; rai[wid] = bi; }
  __syncthreads();
  float ent = -((rps[0] + rps[1]) + (rps[2] + rps[3]));
  float bv2 = rav[0]; int sym = rai[0];
#pragma unroll
  for (int w2 = 1; w2 < 4; w2++) {
    if (rav[w2] > bv2 || (rav[w2] == bv2 && rai[w2] < sym)) { bv2 = rav[w2]; sym = rai[w2]; }
  }
  const u16* gh = ebH + (size_t)sym * E_;
  const u16* gm = ebM + (size_t)sym * E_;
  const u16* gl = ebL + (size_t)sym * E_;
  for (int k2 = tid; k2 < E_; k2 += 256) {
    eh[(size_t)b * E_ + k2]  = gh[k2];
    em_[(size_t)b * E_ + k2] = gm[k2];
    el_[(size_t)b * E_ + k2] = gl[k2];
  }
  if (tid == 0) {
    float s_sym = (zs[sym] - m) - ls;
    o_seq[b * LP1 + t] = (float)sym;
    o_logp[b * LP1 + t] = s_sym;
    o_ent[b * LP1 + t] = ent;
  }
}

extern "C" void kernel_launch(void* const* d_in, const int* in_sizes, int n_in,
                              void* d_out, int out_size, void* d_ws, size_t ws_size,
                              hipStream_t stream) {
  (void)in_sizes; (void)n_in; (void)out_size; (void)ws_size;
  const float* x     = (const float*)d_in[0];
  const float* agw   = (const float*)d_in[1];
  const float* agb   = (const float*)d_in[2];
  const float* sos   = (const float*)d_in[3];
  const float* emb   = (const float*)d_in[4];
  const float* w_ih  = (const float*)d_in[5];
  const float* w_hh  = (const float*)d_in[6];
  const float* b_ih  = (const float*)d_in[7];
  const float* b_hh  = (const float*)d_in[8];
  const float* out_w = (const float*)d_in[9];
  const float* out_b = (const float*)d_in[10];

  char* w = (char*)d_ws;
  size_t o = 0;
  uint32_t* sk = (uint32_t*)(w + o); o += 1024;
  float* c = (float*)(w + o);        o += (size_t)B_ * H_ * 4;          // 1 MB
#define PLANE3(name, elems) \
  u16* name##H = (u16*)(w + o); o += (size_t)(elems) * 2; \
  u16* name##M = (u16*)(w + o); o += (size_t)(elems) * 2; \
  u16* name##L = (u16*)(w + o); o += (size_t)(elems) * 2;
  PLANE3(e,  B_ * E_)          // 1.5 MB  e activations
  PLANE3(hA, B_ * H_)          // 1.5 MB  h ping
  PLANE3(hB, B_ * H_)          // 1.5 MB  h pong
  PLANE3(xp, B_ * IN_)         // 3 MB    x
  PLANE3(aw, H_ * IN_)         // 3 MB    agent_w^T   [512][1024]
  PLANE3(gw, 2048 * IN_)       // 12 MB   [w_ih;w_hh]^T [2048][1024]
  PLANE3(ow, V_ * H_)          // 6 MB    out_w^T     [2048][512]
  PLANE3(eb, V_ * E_)          // 6 MB    embedding   [2048][512]
#undef PLANE3
  float* P = (float*)(w + o);        // 16 MB partials

  float* out = (float*)d_out;
  float* o_seq   = out;                                       // [512,33]
  float* o_probs = out + (size_t)B_ * LP1;                    // [512,33,2048]
  float* o_logp  = o_probs + (size_t)B_ * LP1 * V_;           // [512,33]
  float* o_ent   = o_logp + (size_t)B_ * LP1;                 // [512,33]

  const int BIG = 1 << 30;

  init_keys_kernel<<<1, 1, 0, stream>>>(sk);
  init_state_planes_kernel<<<(B_ * H_ + 255) / 256, 256, 0, stream>>>(sos, c, eH, eM, eL);
  eos_fill_kernel<<<B_, 256, 0, stream>>>(o_seq, o_probs, o_logp, o_ent);

  // one-time conversions
  split_kernel<<<(B_ * IN_ + 255) / 256, 256, 0, stream>>>(x, xpH, xpM, xpL, B_ * IN_);
  split_kernel<<<(V_ * E_ + 255) / 256, 256, 0, stream>>>(emb, ebH, ebM, ebL, V_ * E_);
  transpose_split_kernel<<<dim3(512 / 32, 2048 / 32), 256, 0, stream>>>(
      w_ih, 2048, gwH, gwM, gwL, 1024, 0);
  transpose_split_kernel<<<dim3(512 / 32, 2048 / 32), 256, 0, stream>>>(
      w_hh, 2048, gwH, gwM, gwL, 1024, 512);
  transpose_split_kernel<<<dim3(512 / 32, 2048 / 32), 256, 0, stream>>>(
      out_w, 2048, owH, owM, owL, 512, 0);
  transpose_split_kernel<<<dim3(1024 / 32, 512 / 32), 256, 0, stream>>>(
      agw, 512, awH, awM, awL, 1024, 0);

  // h0 = x @ agent_w + agent_b   (M=512,N=512,K=1024; split-K 16 -> 256 blocks)
  gemm3_kernel<<<dim3(4, 4, SPLITK_H0), 256, 0, stream>>>(
      xpH, xpM, xpL, xpH, xpM, xpL, IN_, BIG,
      awH, awM, awL, IN_, H_, IN_ / SPLITK_H0, P, PSTRIDE_H0);
  reduce_bias_planes_kernel<<<(B_ * H_ / 4 + 255) / 256, 256, 0, stream>>>(
      P, PSTRIDE_H0, SPLITK_H0, agb, hAH, hAM, hAL);

  for (int t = 0; t < LSTEPS; t++) {
    u16 *hiH = (t & 1) ? hBH : hAH, *hiM = (t & 1) ? hBM : hAM, *hiL = (t & 1) ? hBL : hAL;
    u16 *hoH = (t & 1) ? hAH : hBH, *hoM = (t & 1) ? hAM : hBM, *hoL = (t & 1) ? hAL : hBL;
    // gates = [e|h] @ [w_ih; w_hh]  (K=1024, KPB=256, kHalf=512)
    gemm3_kernel<<<dim3(4, 16, SPLITK), 256, 0, stream>>>(
        eH, eM, eL, hiH, hiM, hiL, E_, E_,
        gwH, gwM, gwL, IN_, 2048, (E_ + H_) / SPLITK, P, PSTRIDE_GATES);
    cell_reduce_planes_kernel<<<B_ * H_ / 4 / 256, 256, 0, stream>>>(
        P, b_ih, b_hh, c, hoH, hoM, hoL);
    // logits partials = h @ out_w  (K=512, KPB=128)
    gemm3_kernel<<<dim3(4, 16, SPLITK), 256, 0, stream>>>(
        hoH, hoM, hoL, hoH, hoM, hoL, H_, BIG,
        owH, owM, owL, H_, 2048, H_ / SPLITK, P, PSTRIDE_GATES);
    sample_step_kernel<<<B_, 256, 0, stream>>>(
        P, out_b, sk, ebH, ebM, ebL, eH, eM, eL,
        o_seq, o_probs, o_logp, o_ent, t);
  }
}